// Round 2
// baseline (1681.350 us; speedup 1.0000x reference)
//
#include <hip/hip_runtime.h>
#include <hip/hip_cooperative_groups.h>
#include <math.h>

namespace cg = cooperative_groups;

// ---------------------------------------------------------------------------
// SpectralConv2d: sigma = tensor-spectral-norm(w) via 20 complex power its,
// then y = conv2d_same(x, w/sigma, NHWC, 3x3) + bias.
// B=32 H=W=64 CIN=COUT=256 KH=KW=3.
// Round 2: (1) conv rebuilt as m97-style LDS-staged MFMA GEMM
//          (2) whole power iteration fused into ONE cooperative kernel
// ---------------------------------------------------------------------------

#define EPSN 1e-12f

// ---- workspace layout (bytes) ----
// xb  : bf16 padded input  [32][66][66][256]             = 71,368,704 B
// wt2 : bf16 weights       [8cc][9tap][256cout][32ci]    =  1,179,648 B
// ctrl: float control area                               =    135,168 B
#define XB_OFF   0
#define WT_OFF   71368704
#define CTRL_OFF 72548352

// ctrl offsets (floats)
#define CTRL_M   0      // M[2][18]   (2 parity slots, 9 complex each)
#define CTRL_NA  576    // sum |a|^2 (final)
#define CTRL_PB  1024   // pb[64][256] complex  (per-block partial b)

struct c2 { float x, y; };
__device__ inline c2 cadd(c2 a, c2 b) { return {a.x + b.x, a.y + b.y}; }
__device__ inline c2 cmul(c2 a, c2 b) { return {a.x * b.x - a.y * b.y, a.x * b.y + a.y * b.x}; }
__device__ inline c2 cjg(c2 a) { return {a.x, -a.y}; }
__device__ inline c2 cscale(c2 a, float s) { return {a.x * s, a.y * s}; }

__device__ inline unsigned short f2bf(float f) {  // RNE fp32->bf16
    unsigned int u = __float_as_uint(f);
    unsigned int r = u + 0x7fffu + ((u >> 16) & 1u);
    return (unsigned short)(r >> 16);
}

typedef __bf16 bf16x8 __attribute__((ext_vector_type(8)));
typedef float  f32x4  __attribute__((ext_vector_type(4)));

__device__ __forceinline__ void gl_lds16(const unsigned short* g, unsigned short* l) {
    __builtin_amdgcn_global_load_lds(
        (const __attribute__((address_space(1))) unsigned int*)g,
        (__attribute__((address_space(3))) unsigned int*)l, 16, 0, 0);
}

// ---------------------------------------------------------------------------
// xprep: x fp32 NHWC -> padded bf16 [32][66][66][256]; also zero ctrl M[0], na
// grid: 34848 x 256
// ---------------------------------------------------------------------------
__global__ __launch_bounds__(256) void k_xprep(const float* __restrict__ x,
                                               unsigned short* __restrict__ xb,
                                               float* __restrict__ ctrl) {
    int flat = blockIdx.x * 256 + threadIdx.x;
    int c4   = flat & 63;
    int rest = flat >> 6;                           // (b*66+hh)*66+ww
    int ww   = rest % 66;
    int r2   = rest / 66;
    int hh   = r2 % 66;
    int b    = r2 / 66;
    int h = hh - 1, w2 = ww - 1;
    ushort4 outv;
    if (h >= 0 && h < 64 && w2 >= 0 && w2 < 64) {
        const float4 v = *(const float4*)(x + ((((b << 6) + h) << 6) + w2) * 256 + (c4 << 2));
        outv.x = f2bf(v.x); outv.y = f2bf(v.y); outv.z = f2bf(v.z); outv.w = f2bf(v.w);
    } else {
        outv.x = 0; outv.y = 0; outv.z = 0; outv.w = 0;
    }
    *(ushort4*)(xb + ((size_t)rest << 8) + (c4 << 2)) = outv;
    if (flat == 0) {
        #pragma unroll
        for (int j = 0; j < 18; ++j) ctrl[CTRL_M + j] = 0.f;   // M slot 0
        ctrl[CTRL_NA] = 0.f;
    }
}

// ---------------------------------------------------------------------------
// k_power: entire 20-iteration power method + sigma + weight transform, fused.
// Cooperative launch: 64 blocks x 1024 threads. thread=(o=bid*4+tid>>8,i=tid&255).
// kr[9] (w row) lives in VGPRs for the whole kernel; c,d,g,a,b in registers.
// Sequence: for t=0..20 { M(t)+=reduce(kr*conj(a*b)); sync;
//                         if t<20: Q(t): d,c from M; g; pb; sync;
//                                  P(t+1): b=N(sum pb); a=sum conj(b)g }
// Tail: sigma from M(20),c_19,||a||; wt2 = bf16(w/sigma).
// ---------------------------------------------------------------------------
__global__ __launch_bounds__(1024) void k_power(const float* __restrict__ w,
                                                const float* __restrict__ u1,
                                                const float* __restrict__ u2,
                                                const float* __restrict__ u3,
                                                float* __restrict__ ctrl,
                                                unsigned short* __restrict__ wt2) {
    cg::grid_group grid = cg::this_grid();
    const int tid  = threadIdx.x, bid = blockIdx.x;
    const int os   = tid >> 8, i = tid & 255;
    const int o    = (bid << 2) + os;
    const int lane = tid & 63, wid = tid >> 6;

    __shared__ float red1[16];
    __shared__ c2    red2[16];
    __shared__ c2    abc[4];
    __shared__ float mred[16][18];
    __shared__ float nbshare;
    __shared__ c2    shbuf[4][256];      // gred / pb-partial, phase-reused

    float kr[9];
    {
        const float* wr = w + (size_t)((o << 8) + i) * 9;
        #pragma unroll
        for (int j = 0; j < 9; ++j) kr[j] = wr[j];
    }

    c2 a_c = ((const c2*)u1)[o];
    c2 b_c = ((const c2*)u2)[i];
    c2 cprev[3];
    #pragma unroll
    for (int h = 0; h < 3; ++h) cprev[h] = ((const c2*)u3)[h];

    for (int t = 0; t <= 20; ++t) {
        // ---- M(t) accumulate into slot t&1 (slot pre-zeroed) ----
        {
            c2 pc = cjg(cmul(a_c, b_c));
            float mv[18];
            #pragma unroll
            for (int hw = 0; hw < 9; ++hw) { mv[2 * hw] = kr[hw] * pc.x; mv[2 * hw + 1] = kr[hw] * pc.y; }
            #pragma unroll
            for (int j = 0; j < 18; ++j)
                #pragma unroll
                for (int off = 32; off; off >>= 1) mv[j] += __shfl_down(mv[j], off);
            if (lane == 0) {
                #pragma unroll
                for (int j = 0; j < 18; ++j) mred[wid][j] = mv[j];
            }
            __syncthreads();
            if (tid < 18) {
                float s3 = 0.f;
                #pragma unroll
                for (int k = 0; k < 16; ++k) s3 += mred[k][tid];
                atomicAdd(ctrl + CTRL_M + (t & 1) * 18 + tid, s3);
            }
        }
        if (t == 20 && i == 0)
            atomicAdd(ctrl + CTRL_NA, a_c.x * a_c.x + a_c.y * a_c.y);
        __threadfence();
        grid.sync();
        if (t == 20) break;

        // ---- Q-part(t): d,c from M[t&1]; g; pb ----
        float m[18];
        #pragma unroll
        for (int j = 0; j < 18; ++j) m[j] = ctrl[CTRL_M + (t & 1) * 18 + j];

        c2 dv[3]; float nd2 = 0.f;
        #pragma unroll
        for (int w2 = 0; w2 < 3; ++w2) {
            c2 s = {0.f, 0.f};
            #pragma unroll
            for (int h = 0; h < 3; ++h) {
                c2 mc = {m[2 * (h * 3 + w2)], m[2 * (h * 3 + w2) + 1]};
                s = cadd(s, cmul(mc, cjg(cprev[h])));
            }
            dv[w2] = s; nd2 += s.x * s.x + s.y * s.y;
        }
        {
            float inv = 1.f / (sqrtf(nd2) + EPSN);
            #pragma unroll
            for (int w2 = 0; w2 < 3; ++w2) dv[w2] = cscale(dv[w2], inv);
        }
        c2 cn[3]; float nc2 = 0.f;
        #pragma unroll
        for (int h = 0; h < 3; ++h) {
            c2 s = {0.f, 0.f};
            #pragma unroll
            for (int w2 = 0; w2 < 3; ++w2) {
                c2 mc = {m[2 * (h * 3 + w2)], m[2 * (h * 3 + w2) + 1]};
                s = cadd(s, cmul(mc, cjg(dv[w2])));
            }
            cn[h] = s; nc2 += s.x * s.x + s.y * s.y;
        }
        {
            float inv = 1.f / (sqrtf(nc2) + EPSN);
            #pragma unroll
            for (int h = 0; h < 3; ++h) cn[h] = cscale(cn[h], inv);
        }
        // zero the other M slot for M(t+1)
        if (bid == 0 && tid < 18) ctrl[CTRL_M + ((t + 1) & 1) * 18 + tid] = 0.f;

        c2 g = {0.f, 0.f};
        #pragma unroll
        for (int h = 0; h < 3; ++h)
            #pragma unroll
            for (int w2 = 0; w2 < 3; ++w2) {
                c2 qv = cjg(cmul(cn[h], dv[w2]));
                g.x += kr[h * 3 + w2] * qv.x;
                g.y += kr[h * 3 + w2] * qv.y;
            }
        __syncthreads();                 // shbuf free from previous phase
        shbuf[os][i] = cmul(cjg(a_c), g);
        __syncthreads();
        if (tid < 256) {
            c2 s = cadd(cadd(shbuf[0][tid], shbuf[1][tid]), cadd(shbuf[2][tid], shbuf[3][tid]));
            ((c2*)(ctrl + CTRL_PB))[(bid << 8) + tid] = s;
        }
        __threadfence();
        grid.sync();

        // ---- P-part(t+1): b = N(sum_p pb); a = sum_i conj(b) g ----
        {
            const c2* pb = (const c2*)(ctrl + CTRL_PB);
            c2 s = {0.f, 0.f};
            #pragma unroll
            for (int p = 0; p < 16; ++p) s = cadd(s, pb[(((os << 4) + p) << 8) + i]);
            __syncthreads();             // shbuf free (tid<256 readers done via grid.sync)
            shbuf[os][i] = s;
        }
        __syncthreads();
        c2 bs = cadd(cadd(shbuf[0][i], shbuf[1][i]), cadd(shbuf[2][i], shbuf[3][i]));
        float n2 = bs.x * bs.x + bs.y * bs.y;      // 4 redundant copies per i
        #pragma unroll
        for (int off = 32; off; off >>= 1) n2 += __shfl_down(n2, off);
        if (lane == 0) red1[wid] = n2;
        __syncthreads();
        if (tid == 0) {
            float acc = 0.f;
            #pragma unroll
            for (int k = 0; k < 16; ++k) acc += red1[k];
            nbshare = sqrtf(acc * 0.25f);
        }
        __syncthreads();
        b_c = cscale(bs, 1.f / (nbshare + EPSN));

        c2 contrib = cmul(cjg(b_c), g);            // g still in registers
        float vx = contrib.x, vy = contrib.y;
        #pragma unroll
        for (int off = 32; off; off >>= 1) { vx += __shfl_down(vx, off); vy += __shfl_down(vy, off); }
        if (lane == 0) red2[wid] = {vx, vy};
        __syncthreads();
        if (tid < 4) {
            c2 s2 = {0.f, 0.f};
            #pragma unroll
            for (int k = 0; k < 4; ++k) s2 = cadd(s2, red2[(tid << 2) + k]);
            abc[tid] = s2;
        }
        __syncthreads();
        a_c = abc[os];
        #pragma unroll
        for (int h = 0; h < 3; ++h) cprev[h] = cn[h];
    }

    // ---- tail: sigma; wt2[cc][tap][cout][ci32] = bf16(w/sigma) ----
    float m[18];
    #pragma unroll
    for (int j = 0; j < 18; ++j) m[j] = ctrl[CTRL_M + j];        // slot 0 = M(20)
    c2 dv[3]; float nd2 = 0.f;
    #pragma unroll
    for (int w2 = 0; w2 < 3; ++w2) {
        c2 s = {0.f, 0.f};
        #pragma unroll
        for (int h = 0; h < 3; ++h) {
            c2 mc = {m[2 * (h * 3 + w2)], m[2 * (h * 3 + w2) + 1]};
            s = cadd(s, cmul(mc, cjg(cprev[h])));                 // cprev = c_19
        }
        dv[w2] = s; nd2 += s.x * s.x + s.y * s.y;
    }
    {
        float inv = 1.f / (sqrtf(nd2) + EPSN);
        #pragma unroll
        for (int w2 = 0; w2 < 3; ++w2) dv[w2] = cscale(dv[w2], inv);
    }
    c2 sg = {0.f, 0.f};
    #pragma unroll
    for (int h = 0; h < 3; ++h)
        #pragma unroll
        for (int w2 = 0; w2 < 3; ++w2) {
            c2 mc = {m[2 * (h * 3 + w2)], m[2 * (h * 3 + w2) + 1]};
            sg = cadd(sg, cmul(mc, cjg(cmul(cprev[h], dv[w2]))));
        }
    float na     = sqrtf(ctrl[CTRL_NA]);
    float invsig = (na + EPSN) / (sqrtf(sg.x * sg.x + sg.y * sg.y) + EPSN);
    const int cc = i >> 5, ci = i & 31;
    #pragma unroll
    for (int tap = 0; tap < 9; ++tap)
        wt2[(size_t)(cc * 9 + tap) * 8192 + (o << 5) + ci] = f2bf(kr[tap] * invsig);
}

// ---------------------------------------------------------------------------
// conv v2: m97-style LDS-staged implicit GEMM.
// Block = 128 pixels (2 rows x 64 cols) x 128 couts, 256 threads, 4 waves
// (2x2 of 64x64). K-loop: 8 cc-chunks x 9 taps; per step stage A 8KB + B 8KB
// via global_load_lds(16B), then 16 MFMA/wave from ds_read_b128.
// grid: 2048.  bid = (pixel_block<<1)|nb ; pixel_block = (b<<5)|hp
// ---------------------------------------------------------------------------
__global__ __launch_bounds__(256) void k_conv(const unsigned short* __restrict__ xb,
                                              const unsigned short* __restrict__ wt2,
                                              const float* __restrict__ bias,
                                              float* __restrict__ y) {
    __shared__ unsigned short lA[4096];   // [128 pix][32 ch]
    __shared__ unsigned short lB[4096];   // [128 cout][32 ci]
    const int tid  = threadIdx.x, bid = blockIdx.x;
    const int lane = tid & 63, wid = tid >> 6;
    const int l15  = lane & 15, q = lane >> 4;
    const int pbk  = bid >> 1, nb = bid & 1;
    const int b    = pbk >> 5, hp = pbk & 31, h0 = hp << 1;
    const int mh   = (wid & 1) << 6;
    const int nq   = (wid >> 1) << 6;
    const int n_off = (nb << 7) + nq;

    // A staging: round j in {0,1}: unit u = j*256+tid -> pixel u>>2, chunk tid&3
    int apix[2];
    #pragma unroll
    for (int j = 0; j < 2; ++j) {
        int p = (j << 6) + (tid >> 2);
        int r = p >> 6, c = p & 63;
        apix[j] = ((b * 66 + h0 + r) * 66 + c) * 256 + (tid & 3) * 8;
    }
    const unsigned short* bgp = wt2 + (nb << 12) + (tid << 3);
    unsigned short* lAd = lA + (tid << 3);
    unsigned short* lBd = lB + (tid << 3);

    f32x4 acc[4][4];
    #pragma unroll
    for (int ms = 0; ms < 4; ++ms)
        #pragma unroll
        for (int ns = 0; ns < 4; ++ns) acc[ms][ns] = {0.f, 0.f, 0.f, 0.f};

    for (int cc = 0; cc < 8; ++cc) {
        #pragma unroll
        for (int tap = 0; tap < 9; ++tap) {
            const int kh = tap / 3, kw = tap % 3;
            const int aoff = (kh * 66 + kw) * 256 + (cc << 5);
            const int boff = ((cc * 9 + tap) << 13);
            __syncthreads();
            #pragma unroll
            for (int j = 0; j < 2; ++j) {
                gl_lds16(xb + apix[j] + aoff, lAd + (j << 11));
                gl_lds16(bgp + boff + (j << 11), lBd + (j << 11));
            }
            __syncthreads();
            bf16x8 av[4], bv[4];
            #pragma unroll
            for (int ms = 0; ms < 4; ++ms)
                av[ms] = *(const bf16x8*)(lA + ((mh + (ms << 4) + l15) << 5) + (q << 3));
            #pragma unroll
            for (int ns = 0; ns < 4; ++ns)
                bv[ns] = *(const bf16x8*)(lB + ((nq + (ns << 4) + l15) << 5) + (q << 3));
            #pragma unroll
            for (int ms = 0; ms < 4; ++ms)
                #pragma unroll
                for (int ns = 0; ns < 4; ++ns)
                    acc[ms][ns] = __builtin_amdgcn_mfma_f32_16x16x32_bf16(
                        av[ms], bv[ns], acc[ms][ns], 0, 0, 0);
        }
    }

    float bias_v[4];
    #pragma unroll
    for (int ns = 0; ns < 4; ++ns) bias_v[ns] = bias[n_off + (ns << 4) + l15];

    #pragma unroll
    for (int ms = 0; ms < 4; ++ms) {
        const int pb2 = mh + (ms << 4) + (q << 2);
        #pragma unroll
        for (int r2 = 0; r2 < 4; ++r2) {
            const int pr = pb2 + r2;
            const int h = h0 + (pr >> 6), wc = pr & 63;
            float* yr = y + ((((b << 6) + h) << 6) + wc) * 256 + n_off;
            #pragma unroll
            for (int ns = 0; ns < 4; ++ns)
                yr[(ns << 4) + l15] = acc[ms][ns][r2] + bias_v[ns];
        }
    }
}

// ---------------------------------------------------------------------------
extern "C" void kernel_launch(void* const* d_in, const int* in_sizes, int n_in,
                              void* d_out, int out_size, void* d_ws, size_t ws_size,
                              hipStream_t stream) {
    const float* x    = (const float*)d_in[0];
    const float* w    = (const float*)d_in[1];
    const float* bias = (const float*)d_in[2];
    const float* u1   = (const float*)d_in[3];   // complex64 interleaved
    const float* u2   = (const float*)d_in[4];
    const float* u3   = (const float*)d_in[5];
    float* y = (float*)d_out;

    char* ws = (char*)d_ws;
    unsigned short* xb = (unsigned short*)(ws + XB_OFF);
    unsigned short* wt = (unsigned short*)(ws + WT_OFF);
    float*          ct = (float*)(ws + CTRL_OFF);

    k_xprep<<<34848, 256, 0, stream>>>(x, xb, ct);

    void* args[] = {(void*)&w, (void*)&u1, (void*)&u2, (void*)&u3, (void*)&ct, (void*)&wt};
    hipLaunchCooperativeKernel((const void*)k_power, dim3(64), dim3(1024), args, 0, stream);

    k_conv<<<2048, 256, 0, stream>>>(xb, wt, bias, y);
}

// Round 3
// 764.549 us; speedup vs baseline: 2.1991x; 2.1991x over previous
//
#include <hip/hip_runtime.h>
#include <math.h>

// ---------------------------------------------------------------------------
// SpectralConv2d: sigma = tensor-spectral-norm(w) via 20 complex power its,
// then y = conv2d_same(x, w/sigma, NHWC, 3x3) + bias.
// B=32 H=W=64 CIN=COUT=256 KH=KW=3.
// Round 3: (1) hand-rolled LLC barrier (agent-scope atomics) replaces the
//              31-us/sync cg::grid.sync in the fused power kernel
//          (2) conv K-loop BK=32 -> BK=64 (m97 config): half the barriers
// ---------------------------------------------------------------------------

#define EPSN 1e-12f

// ---- workspace layout (bytes) ----
// xb  : bf16 padded input  [32][66][66][256]          = 71,368,704 B
// wt3 : bf16 weights       [9tap][256cout][256ci]     =  1,179,648 B
// ctrl: float control area (33792 floats)             =    135,168 B
#define XB_OFF   0
#define WT_OFF   71368704
#define CTRL_OFF 72548352

// ctrl offsets (floats). All cross-block data accessed via AGENT-scope
// atomics only (coherent at LLC; per-XCD L2s never hold it).
#define CTRL_BAR 0      // int bar[64]   barrier arrival slots (one per sync)
#define CTRL_M   64     // M[21][18]     unique slot per iteration
#define CTRL_NA  448    // sum |a|^2
#define CTRL_PB  1024   // pb[64][256] complex (overwrite-only, no zeroing)

#define NPB 64          // power-kernel blocks

struct c2 { float x, y; };
__device__ inline c2 cadd(c2 a, c2 b) { return {a.x + b.x, a.y + b.y}; }
__device__ inline c2 cmul(c2 a, c2 b) { return {a.x * b.x - a.y * b.y, a.x * b.y + a.y * b.x}; }
__device__ inline c2 cjg(c2 a) { return {a.x, -a.y}; }
__device__ inline c2 cscale(c2 a, float s) { return {a.x * s, a.y * s}; }

__device__ inline unsigned short f2bf(float f) {  // RNE fp32->bf16
    unsigned int u = __float_as_uint(f);
    unsigned int r = u + 0x7fffu + ((u >> 16) & 1u);
    return (unsigned short)(r >> 16);
}

typedef __bf16 bf16x8 __attribute__((ext_vector_type(8)));
typedef float  f32x4  __attribute__((ext_vector_type(4)));

__device__ __forceinline__ void gl_lds16(const unsigned short* g, unsigned short* l) {
    __builtin_amdgcn_global_load_lds(
        (const __attribute__((address_space(1))) unsigned int*)g,
        (__attribute__((address_space(3))) unsigned int*)l, 16, 0, 0);
}

// agent-scope helpers (bypass non-coherent L2, live at LLC)
__device__ __forceinline__ float ald(const float* p) {
    return __hip_atomic_load(p, __ATOMIC_RELAXED, __HIP_MEMORY_SCOPE_AGENT);
}
__device__ __forceinline__ void aadd(float* p, float v) {
    __hip_atomic_fetch_add(p, v, __ATOMIC_RELAXED, __HIP_MEMORY_SCOPE_AGENT);
}
__device__ __forceinline__ void ast64(unsigned long long* p, c2 v) {
    union { c2 c; unsigned long long u; } cv; cv.c = v;
    __hip_atomic_store(p, cv.u, __ATOMIC_RELAXED, __HIP_MEMORY_SCOPE_AGENT);
}
__device__ __forceinline__ c2 ald64(const unsigned long long* p) {
    union { c2 c; unsigned long long u; } cv;
    cv.u = __hip_atomic_load(p, __ATOMIC_RELAXED, __HIP_MEMORY_SCOPE_AGENT);
    return cv.c;
}

// Device barrier over NPB blocks. Requires co-residency (cooperative launch).
// Writers' vmcnt drained by the entry __syncthreads; RELEASE on the arrival
// add orders it; readers use agent-scope loads so no invalidate needed.
__device__ __forceinline__ void gbar(int* bar, int slot, int tid) {
    __syncthreads();
    if (tid == 0) {
        __hip_atomic_fetch_add(&bar[slot], 1, __ATOMIC_RELEASE, __HIP_MEMORY_SCOPE_AGENT);
        while (__hip_atomic_load(&bar[slot], __ATOMIC_RELAXED, __HIP_MEMORY_SCOPE_AGENT) < NPB)
            __builtin_amdgcn_s_sleep(1);
    }
    __syncthreads();
}

// ---------------------------------------------------------------------------
// xprep: x fp32 NHWC -> padded bf16 [32][66][66][256]; block 0 zeroes ctrl.
// grid: 34848 x 256
// ---------------------------------------------------------------------------
__global__ __launch_bounds__(256) void k_xprep(const float* __restrict__ x,
                                               unsigned short* __restrict__ xb,
                                               float* __restrict__ ctrl) {
    int flat = blockIdx.x * 256 + threadIdx.x;
    int c4   = flat & 63;
    int rest = flat >> 6;                           // (b*66+hh)*66+ww
    int ww   = rest % 66;
    int r2   = rest / 66;
    int hh   = r2 % 66;
    int b    = r2 / 66;
    int h = hh - 1, w2 = ww - 1;
    ushort4 outv;
    if (h >= 0 && h < 64 && w2 >= 0 && w2 < 64) {
        const float4 v = *(const float4*)(x + ((((b << 6) + h) << 6) + w2) * 256 + (c4 << 2));
        outv.x = f2bf(v.x); outv.y = f2bf(v.y); outv.z = f2bf(v.z); outv.w = f2bf(v.w);
    } else {
        outv.x = 0; outv.y = 0; outv.z = 0; outv.w = 0;
    }
    *(ushort4*)(xb + ((size_t)rest << 8) + (c4 << 2)) = outv;
    if (blockIdx.x == 0 && threadIdx.x < 256) {     // zero bar/M/NA (first 512 floats)
        ctrl[threadIdx.x]       = 0.f;
        ctrl[threadIdx.x + 256] = 0.f;
    }
}

// ---------------------------------------------------------------------------
// k_power: entire 20-iteration power method + sigma + weight transform, fused.
// Cooperative launch: 64 blocks x 1024. thread=(o=bid*4+tid>>8, i=tid&255).
// kr[9] in VGPRs throughout; a,b,c,d,g in registers; cross-block M/pb/NA via
// agent atomics + gbar (2 barriers per iteration, 41 total).
// ---------------------------------------------------------------------------
__global__ __launch_bounds__(1024) void k_power(const float* __restrict__ w,
                                                const float* __restrict__ u1,
                                                const float* __restrict__ u2,
                                                const float* __restrict__ u3,
                                                float* __restrict__ ctrl,
                                                unsigned short* __restrict__ wt3) {
    const int tid  = threadIdx.x, bid = blockIdx.x;
    const int os   = tid >> 8, i = tid & 255;
    const int o    = (bid << 2) + os;
    const int lane = tid & 63, wid = tid >> 6;

    int*                bar   = (int*)(ctrl + CTRL_BAR);
    unsigned long long* pbull = (unsigned long long*)(ctrl + CTRL_PB);

    __shared__ float red1[16];
    __shared__ c2    red2[16];
    __shared__ c2    abc[4];
    __shared__ float mred[16][18];
    __shared__ float nbshare;
    __shared__ float msm[18];
    __shared__ c2    shbuf[4][256];

    float kr[9];
    {
        const float* wr = w + (size_t)((o << 8) + i) * 9;
        #pragma unroll
        for (int j = 0; j < 9; ++j) kr[j] = wr[j];
    }

    c2 a_c = ((const c2*)u1)[o];
    c2 b_c = ((const c2*)u2)[i];
    c2 cprev[3];
    #pragma unroll
    for (int h = 0; h < 3; ++h) cprev[h] = ((const c2*)u3)[h];

    for (int t = 0; t <= 20; ++t) {
        // ---- M(t) accumulate into unique slot t (pre-zeroed by xprep) ----
        {
            c2 pc = cjg(cmul(a_c, b_c));
            float mv[18];
            #pragma unroll
            for (int hw = 0; hw < 9; ++hw) { mv[2 * hw] = kr[hw] * pc.x; mv[2 * hw + 1] = kr[hw] * pc.y; }
            #pragma unroll
            for (int j = 0; j < 18; ++j)
                #pragma unroll
                for (int off = 32; off; off >>= 1) mv[j] += __shfl_down(mv[j], off);
            if (lane == 0) {
                #pragma unroll
                for (int j = 0; j < 18; ++j) mred[wid][j] = mv[j];
            }
            __syncthreads();
            if (tid < 18) {
                float s3 = 0.f;
                #pragma unroll
                for (int k = 0; k < 16; ++k) s3 += mred[k][tid];
                aadd(ctrl + CTRL_M + t * 18 + tid, s3);
            }
        }
        if (t == 20 && i == 0)
            aadd(ctrl + CTRL_NA, a_c.x * a_c.x + a_c.y * a_c.y);
        gbar(bar, 2 * t, tid);
        // stage M(t) through LDS (18 agent loads per block, broadcast)
        if (tid < 18) msm[tid] = ald(ctrl + CTRL_M + t * 18 + tid);
        __syncthreads();
        if (t == 20) break;

        // ---- Q-part(t): d,c from M; g; pb ----
        float m[18];
        #pragma unroll
        for (int j = 0; j < 18; ++j) m[j] = msm[j];

        c2 dv[3]; float nd2 = 0.f;
        #pragma unroll
        for (int w2 = 0; w2 < 3; ++w2) {
            c2 s = {0.f, 0.f};
            #pragma unroll
            for (int h = 0; h < 3; ++h) {
                c2 mc = {m[2 * (h * 3 + w2)], m[2 * (h * 3 + w2) + 1]};
                s = cadd(s, cmul(mc, cjg(cprev[h])));
            }
            dv[w2] = s; nd2 += s.x * s.x + s.y * s.y;
        }
        {
            float inv = 1.f / (sqrtf(nd2) + EPSN);
            #pragma unroll
            for (int w2 = 0; w2 < 3; ++w2) dv[w2] = cscale(dv[w2], inv);
        }
        c2 cn[3]; float nc2 = 0.f;
        #pragma unroll
        for (int h = 0; h < 3; ++h) {
            c2 s = {0.f, 0.f};
            #pragma unroll
            for (int w2 = 0; w2 < 3; ++w2) {
                c2 mc = {m[2 * (h * 3 + w2)], m[2 * (h * 3 + w2) + 1]};
                s = cadd(s, cmul(mc, cjg(dv[w2])));
            }
            cn[h] = s; nc2 += s.x * s.x + s.y * s.y;
        }
        {
            float inv = 1.f / (sqrtf(nc2) + EPSN);
            #pragma unroll
            for (int h = 0; h < 3; ++h) cn[h] = cscale(cn[h], inv);
        }

        c2 g = {0.f, 0.f};
        #pragma unroll
        for (int h = 0; h < 3; ++h)
            #pragma unroll
            for (int w2 = 0; w2 < 3; ++w2) {
                c2 qv = cjg(cmul(cn[h], dv[w2]));
                g.x += kr[h * 3 + w2] * qv.x;
                g.y += kr[h * 3 + w2] * qv.y;
            }
        __syncthreads();
        shbuf[os][i] = cmul(cjg(a_c), g);
        __syncthreads();
        if (tid < 256) {
            c2 s = cadd(cadd(shbuf[0][tid], shbuf[1][tid]), cadd(shbuf[2][tid], shbuf[3][tid]));
            ast64(pbull + (bid << 8) + tid, s);
        }
        gbar(bar, 2 * t + 1, tid);

        // ---- P-part(t+1): b = N(sum_p pb); a = sum_i conj(b) g ----
        {
            c2 s = {0.f, 0.f};
            #pragma unroll 4
            for (int p = 0; p < 16; ++p)
                s = cadd(s, ald64(pbull + (((os << 4) + p) << 8) + i));
            __syncthreads();
            shbuf[os][i] = s;
        }
        __syncthreads();
        c2 bs = cadd(cadd(shbuf[0][i], shbuf[1][i]), cadd(shbuf[2][i], shbuf[3][i]));
        float n2 = bs.x * bs.x + bs.y * bs.y;      // 4 redundant copies per i
        #pragma unroll
        for (int off = 32; off; off >>= 1) n2 += __shfl_down(n2, off);
        if (lane == 0) red1[wid] = n2;
        __syncthreads();
        if (tid == 0) {
            float acc = 0.f;
            #pragma unroll
            for (int k = 0; k < 16; ++k) acc += red1[k];
            nbshare = sqrtf(acc * 0.25f);
        }
        __syncthreads();
        b_c = cscale(bs, 1.f / (nbshare + EPSN));

        c2 contrib = cmul(cjg(b_c), g);
        float vx = contrib.x, vy = contrib.y;
        #pragma unroll
        for (int off = 32; off; off >>= 1) { vx += __shfl_down(vx, off); vy += __shfl_down(vy, off); }
        if (lane == 0) red2[wid] = {vx, vy};
        __syncthreads();
        if (tid < 4) {
            c2 s2 = {0.f, 0.f};
            #pragma unroll
            for (int k = 0; k < 4; ++k) s2 = cadd(s2, red2[(tid << 2) + k]);
            abc[tid] = s2;
        }
        __syncthreads();
        a_c = abc[os];
        #pragma unroll
        for (int h = 0; h < 3; ++h) cprev[h] = cn[h];
    }

    // ---- tail: sigma; wt3[tap][o][ci] = bf16(w/sigma) ----
    float m[18];
    #pragma unroll
    for (int j = 0; j < 18; ++j) m[j] = msm[j];                  // M(20)
    c2 dv[3]; float nd2 = 0.f;
    #pragma unroll
    for (int w2 = 0; w2 < 3; ++w2) {
        c2 s = {0.f, 0.f};
        #pragma unroll
        for (int h = 0; h < 3; ++h) {
            c2 mc = {m[2 * (h * 3 + w2)], m[2 * (h * 3 + w2) + 1]};
            s = cadd(s, cmul(mc, cjg(cprev[h])));                 // cprev = c_19
        }
        dv[w2] = s; nd2 += s.x * s.x + s.y * s.y;
    }
    {
        float inv = 1.f / (sqrtf(nd2) + EPSN);
        #pragma unroll
        for (int w2 = 0; w2 < 3; ++w2) dv[w2] = cscale(dv[w2], inv);
    }
    c2 sg = {0.f, 0.f};
    #pragma unroll
    for (int h = 0; h < 3; ++h)
        #pragma unroll
        for (int w2 = 0; w2 < 3; ++w2) {
            c2 mc = {m[2 * (h * 3 + w2)], m[2 * (h * 3 + w2) + 1]};
            sg = cadd(sg, cmul(mc, cjg(cmul(cprev[h], dv[w2]))));
        }
    float na     = sqrtf(ald(ctrl + CTRL_NA));
    float invsig = (na + EPSN) / (sqrtf(sg.x * sg.x + sg.y * sg.y) + EPSN);
    #pragma unroll
    for (int tap = 0; tap < 9; ++tap)
        wt3[(size_t)tap * 65536 + (o << 8) + i] = f2bf(kr[tap] * invsig);
}

// ---------------------------------------------------------------------------
// conv v3: LDS-staged implicit GEMM, BK=64 (m97 config).
// Block = 128 pixels (2 rows x 64 cols) x 128 couts, 256 threads, 4 waves
// (2x2 of 64x64). 36 staging rounds (9 taps x 4 cc64); per round stage
// A 16KB + B 16KB via global_load_lds(16B), then 32 MFMA/wave.
// LDS layout [ks][128][32] keeps the measured conflict-free pattern.
// grid: 2048.  bid = (pixel_block<<1)|nb ; pixel_block = (b<<5)|hp
// ---------------------------------------------------------------------------
__global__ __launch_bounds__(256) void k_conv(const unsigned short* __restrict__ xb,
                                              const unsigned short* __restrict__ wt3,
                                              const float* __restrict__ bias,
                                              float* __restrict__ y) {
    __shared__ unsigned short lA[8192];   // [2 ks][128 pix][32 ch]
    __shared__ unsigned short lB[8192];   // [2 ks][128 cout][32 ci]
    const int tid  = threadIdx.x, bid = blockIdx.x;
    const int lane = tid & 63, wid = tid >> 6;
    const int l15  = lane & 15, q = lane >> 4;
    const int pbk  = bid >> 1, nb = bid & 1;
    const int b    = pbk >> 5, hp = pbk & 31, h0 = hp << 1;
    const int mh   = (wid & 1) << 6;
    const int nq   = (wid >> 1) << 6;
    const int n_off = (nb << 7) + nq;

    // staging unit u = j*256+tid (j=0..3): elem = (u>>9)*32 + (u&3)*8 within
    // the 64-ch K-block; pix/cout = (u>>2)&127 ; LDS off = u*8 ushorts.
    int ag[4], bg[4];
    #pragma unroll
    for (int j = 0; j < 4; ++j) {
        int u   = (j << 8) + tid;
        int pix = (u >> 2) & 127;
        int ce  = ((u >> 9) << 5) + ((u & 3) << 3);
        int r   = pix >> 6, c = pix & 63;
        ag[j] = ((b * 66 + h0 + r) * 66 + c) * 256 + ce;
        bg[j] = (nb << 15) + (pix << 8) + ce;          // pix plays cout_local
    }
    unsigned short* lAd = lA + (tid << 3);
    unsigned short* lBd = lB + (tid << 3);

    f32x4 acc[4][4];
    #pragma unroll
    for (int ms = 0; ms < 4; ++ms)
        #pragma unroll
        for (int ns = 0; ns < 4; ++ns) acc[ms][ns] = {0.f, 0.f, 0.f, 0.f};

    #pragma unroll 1
    for (int tap = 0; tap < 9; ++tap) {
        const int kh = tap / 3, kw = tap % 3;
        const int aoff = (kh * 66 + kw) * 256;
        const int boff = tap << 16;
        #pragma unroll 1
        for (int cc = 0; cc < 4; ++cc) {
            const int cco = cc << 6;
            __syncthreads();
            #pragma unroll
            for (int j = 0; j < 4; ++j) {
                gl_lds16(xb  + ag[j] + aoff + cco, lAd + (j << 11));
                gl_lds16(wt3 + bg[j] + boff + cco, lBd + (j << 11));
            }
            __syncthreads();
            #pragma unroll
            for (int ks = 0; ks < 2; ++ks) {
                bf16x8 av[4], bv[4];
                #pragma unroll
                for (int ms = 0; ms < 4; ++ms)
                    av[ms] = *(const bf16x8*)(lA + (ks << 12) + ((mh + (ms << 4) + l15) << 5) + (q << 3));
                #pragma unroll
                for (int ns = 0; ns < 4; ++ns)
                    bv[ns] = *(const bf16x8*)(lB + (ks << 12) + ((nq + (ns << 4) + l15) << 5) + (q << 3));
                #pragma unroll
                for (int ms = 0; ms < 4; ++ms)
                    #pragma unroll
                    for (int ns = 0; ns < 4; ++ns)
                        acc[ms][ns] = __builtin_amdgcn_mfma_f32_16x16x32_bf16(
                            av[ms], bv[ns], acc[ms][ns], 0, 0, 0);
            }
        }
    }

    float bias_v[4];
    #pragma unroll
    for (int ns = 0; ns < 4; ++ns) bias_v[ns] = bias[n_off + (ns << 4) + l15];

    #pragma unroll
    for (int ms = 0; ms < 4; ++ms) {
        const int pb2 = mh + (ms << 4) + (q << 2);
        #pragma unroll
        for (int r2 = 0; r2 < 4; ++r2) {
            const int pr = pb2 + r2;
            const int h = h0 + (pr >> 6), wc = pr & 63;
            float* yr = y + ((((b << 6) + h) << 6) + wc) * 256 + n_off;
            #pragma unroll
            for (int ns = 0; ns < 4; ++ns)
                yr[(ns << 4) + l15] = acc[ms][ns][r2] + bias_v[ns];
        }
    }
}

// ---------------------------------------------------------------------------
extern "C" void kernel_launch(void* const* d_in, const int* in_sizes, int n_in,
                              void* d_out, int out_size, void* d_ws, size_t ws_size,
                              hipStream_t stream) {
    const float* x    = (const float*)d_in[0];
    const float* w    = (const float*)d_in[1];
    const float* bias = (const float*)d_in[2];
    const float* u1   = (const float*)d_in[3];   // complex64 interleaved
    const float* u2   = (const float*)d_in[4];
    const float* u3   = (const float*)d_in[5];
    float* y = (float*)d_out;

    char* ws = (char*)d_ws;
    unsigned short* xb = (unsigned short*)(ws + XB_OFF);
    unsigned short* wt = (unsigned short*)(ws + WT_OFF);
    float*          ct = (float*)(ws + CTRL_OFF);

    k_xprep<<<34848, 256, 0, stream>>>(x, xb, ct);

    void* args[] = {(void*)&w, (void*)&u1, (void*)&u2, (void*)&u3, (void*)&ct, (void*)&wt};
    hipLaunchCooperativeKernel((const void*)k_power, dim3(NPB), dim3(1024), args, 0, stream);

    k_conv<<<2048, 256, 0, stream>>>(xb, wt, bias, y);
}